// Round 1
// baseline (517.956 us; speedup 1.0000x reference)
//
#include <hip/hip_runtime.h>
#include <hip/hip_bf16.h>
#include <math.h>

#define BATCH 1024
#define SL    20
#define HID   128

// One block per batch element. 128 threads (2 waves); thread t owns hidden column t.
// Phases (LDS-staged, barriers between):
//   P0: gather emb rows, L2-normalize (skip whole-table norm: only gathered rows matter),
//       gather time_tab -> out, accumulate hidden_avg -> out.
//   P1: hin = h@W_in^T + b_in ; hout = h@W_out^T + b_out   (weights reg-cached, h from LDS broadcast)
//   P2: msg_in = A_in@hin + b_iah ; msg_out = A_out@hout + b_oah  (written in place over hin/hout = cat)
//   P3: gi = cat@w_ih^T + b_ih ; gh = h@w_hh^T + b_hh ; GRU gates -> out hidden.
// LDS = 3*10240 + 3200 + 8 = 33,928 B -> 4 blocks/CU.
__global__ __launch_bounds__(128, 2) void session_graph_kernel(
    const int*   __restrict__ inputs,
    const float* __restrict__ A,
    const int*   __restrict__ times,
    const float* __restrict__ emb,
    const float* __restrict__ time_tab,
    const float* __restrict__ W_in,  const float* __restrict__ b_in,
    const float* __restrict__ W_out, const float* __restrict__ b_out,
    const float* __restrict__ w_ih,  const float* __restrict__ b_ih,
    const float* __restrict__ w_hh,  const float* __restrict__ b_hh,
    const float* __restrict__ b_iah, const float* __restrict__ b_oah,
    float* __restrict__ out)
{
    __shared__ float sh_h0[SL][HID];   // normalized gathered hidden
    __shared__ float sh_c1[SL][HID];   // hin, then cat[:, :128]
    __shared__ float sh_c2[SL][HID];   // hout, then cat[:, 128:]
    __shared__ float sh_A [SL * 2 * SL];
    __shared__ float sh_red[2];

    const int b = blockIdx.x;
    const int t = threadIdx.x;  // 0..127

    float* __restrict__ out_hidden = out;
    float* __restrict__ out_time   = out + (size_t)BATCH * SL * HID;
    float* __restrict__ out_avg    = out + (size_t)2 * BATCH * SL * HID;

    // ---------------- P0: gather + row L2-norm + time gather + avg ----------------
    float avg = 0.f;
    for (int l = 0; l < SL; ++l) {
        const int idx = inputs[b * SL + l];
        const float v = emb[(size_t)idx * HID + t];
        float ss = v * v;
        #pragma unroll
        for (int off = 32; off > 0; off >>= 1) ss += __shfl_xor(ss, off, 64);
        if ((t & 63) == 0) sh_red[t >> 6] = ss;
        __syncthreads();
        const float h0 = v * rsqrtf(sh_red[0] + sh_red[1]);
        sh_h0[l][t] = h0;
        avg += h0;
        const int tt = times[b * SL + l];
        out_time[(size_t)(b * SL + l) * HID + t] = time_tab[tt * HID + t];
        __syncthreads();  // protect sh_red for next iteration
    }
    out_avg[(size_t)b * HID + t] = avg * (1.f / SL);

    // stage A[b] (800 floats, coalesced)
    for (int i = t; i < SL * 2 * SL; i += 128) sh_A[i] = A[(size_t)b * SL * 2 * SL + i];
    __syncthreads();

    // ---------------- P1: hin / hout ----------------
    float a1[SL], a2[SL];
    #pragma unroll
    for (int l = 0; l < SL; ++l) { a1[l] = 0.f; a2[l] = 0.f; }
    {
        const float4* wi4 = (const float4*)(W_in  + (size_t)t * HID);
        const float4* wo4 = (const float4*)(W_out + (size_t)t * HID);
        for (int k = 0; k < HID / 4; ++k) {
            const float4 wi = wi4[k];
            const float4 wo = wo4[k];
            #pragma unroll
            for (int l = 0; l < SL; ++l) {
                const float4 h4 = *(const float4*)&sh_h0[l][k * 4];
                a1[l] += wi.x * h4.x + wi.y * h4.y + wi.z * h4.z + wi.w * h4.w;
                a2[l] += wo.x * h4.x + wo.y * h4.y + wo.z * h4.z + wo.w * h4.w;
            }
        }
    }
    {
        const float bi = b_in[t], bo = b_out[t];
        #pragma unroll
        for (int l = 0; l < SL; ++l) {
            sh_c1[l][t] = a1[l] + bi;
            sh_c2[l][t] = a2[l] + bo;
        }
    }
    __syncthreads();

    // ---------------- P2: adjacency message passing ----------------
    #pragma unroll
    for (int l = 0; l < SL; ++l) { a1[l] = 0.f; a2[l] = 0.f; }
    for (int j = 0; j < SL; ++j) {
        const float hi = sh_c1[j][t];
        const float ho = sh_c2[j][t];
        #pragma unroll
        for (int l = 0; l < SL; ++l) {
            a1[l] += sh_A[l * (2 * SL) + j]      * hi;
            a2[l] += sh_A[l * (2 * SL) + SL + j] * ho;
        }
    }
    __syncthreads();  // all reads of sh_c1/sh_c2 complete
    {
        const float biah = b_iah[t], boah = b_oah[t];
        #pragma unroll
        for (int l = 0; l < SL; ++l) {
            sh_c1[l][t] = a1[l] + biah;   // cat[:, :128]
            sh_c2[l][t] = a2[l] + boah;   // cat[:, 128:]
        }
    }
    __syncthreads();

    // ---------------- P3: gi/gh + GRU gates ----------------
    float gr[SL], gz[SL], gni[SL], gnh[SL];
    #pragma unroll
    for (int l = 0; l < SL; ++l) { gr[l] = 0.f; gz[l] = 0.f; gni[l] = 0.f; gnh[l] = 0.f; }

    const float4* wr4 = (const float4*)(w_ih + (size_t)(t      ) * (2 * HID));
    const float4* wz4 = (const float4*)(w_ih + (size_t)(t + 128) * (2 * HID));
    const float4* wn4 = (const float4*)(w_ih + (size_t)(t + 256) * (2 * HID));
    // gi, first half of cat (in-message)
    for (int k = 0; k < HID / 4; ++k) {
        const float4 wr = wr4[k], wz = wz4[k], wn = wn4[k];
        #pragma unroll
        for (int l = 0; l < SL; ++l) {
            const float4 c = *(const float4*)&sh_c1[l][k * 4];
            gr[l]  += wr.x * c.x + wr.y * c.y + wr.z * c.z + wr.w * c.w;
            gz[l]  += wz.x * c.x + wz.y * c.y + wz.z * c.z + wz.w * c.w;
            gni[l] += wn.x * c.x + wn.y * c.y + wn.z * c.z + wn.w * c.w;
        }
    }
    // gi, second half of cat (out-message)
    for (int k = 0; k < HID / 4; ++k) {
        const float4 wr = wr4[HID / 4 + k], wz = wz4[HID / 4 + k], wn = wn4[HID / 4 + k];
        #pragma unroll
        for (int l = 0; l < SL; ++l) {
            const float4 c = *(const float4*)&sh_c2[l][k * 4];
            gr[l]  += wr.x * c.x + wr.y * c.y + wr.z * c.z + wr.w * c.w;
            gz[l]  += wz.x * c.x + wz.y * c.y + wz.z * c.z + wz.w * c.w;
            gni[l] += wn.x * c.x + wn.y * c.y + wn.z * c.z + wn.w * c.w;
        }
    }
    // gh over original h
    {
        const float4* hr4 = (const float4*)(w_hh + (size_t)(t      ) * HID);
        const float4* hz4 = (const float4*)(w_hh + (size_t)(t + 128) * HID);
        const float4* hn4 = (const float4*)(w_hh + (size_t)(t + 256) * HID);
        for (int k = 0; k < HID / 4; ++k) {
            const float4 wr = hr4[k], wz = hz4[k], wn = hn4[k];
            #pragma unroll
            for (int l = 0; l < SL; ++l) {
                const float4 h4 = *(const float4*)&sh_h0[l][k * 4];
                gr[l]  += wr.x * h4.x + wr.y * h4.y + wr.z * h4.z + wr.w * h4.w;
                gz[l]  += wz.x * h4.x + wz.y * h4.y + wz.z * h4.z + wz.w * h4.w;
                gnh[l] += wn.x * h4.x + wn.y * h4.y + wn.z * h4.z + wn.w * h4.w;
            }
        }
    }
    {
        const float br  = b_ih[t]       + b_hh[t];
        const float bz  = b_ih[t + 128] + b_hh[t + 128];
        const float bni = b_ih[t + 256];
        const float bnh = b_hh[t + 256];
        #pragma unroll
        for (int l = 0; l < SL; ++l) {
            const float r  = 1.f / (1.f + __expf(-(gr[l] + br)));
            const float zg = 1.f / (1.f + __expf(-(gz[l] + bz)));
            const float ng = tanhf(gni[l] + bni + r * (gnh[l] + bnh));
            const float h  = sh_h0[l][t];
            out_hidden[(size_t)(b * SL + l) * HID + t] = ng + zg * (h - ng);
        }
    }
}

extern "C" void kernel_launch(void* const* d_in, const int* in_sizes, int n_in,
                              void* d_out, int out_size, void* d_ws, size_t ws_size,
                              hipStream_t stream)
{
    const int*   inputs = (const int*)  d_in[0];
    const float* A      = (const float*)d_in[1];
    const int*   times  = (const int*)  d_in[2];
    const float* emb    = (const float*)d_in[3];
    const float* ttab   = (const float*)d_in[4];
    const float* W_in   = (const float*)d_in[5];
    const float* b_in   = (const float*)d_in[6];
    const float* W_out  = (const float*)d_in[7];
    const float* b_out  = (const float*)d_in[8];
    const float* w_ih   = (const float*)d_in[9];
    const float* b_ih   = (const float*)d_in[10];
    const float* w_hh   = (const float*)d_in[11];
    const float* b_hh   = (const float*)d_in[12];
    const float* b_iah  = (const float*)d_in[13];
    const float* b_oah  = (const float*)d_in[14];
    float* out = (float*)d_out;

    hipLaunchKernelGGL(session_graph_kernel, dim3(BATCH), dim3(128), 0, stream,
                       inputs, A, times, emb, ttab, W_in, b_in, W_out, b_out,
                       w_ih, b_ih, w_hh, b_hh, b_iah, b_oah, out);
}

// Round 2
// 391.304 us; speedup vs baseline: 1.3237x; 1.3237x over previous
//
#include <hip/hip_runtime.h>
#include <hip/hip_bf16.h>
#include <math.h>

#define BATCH 1024
#define SL    20
#define HID   128

typedef __attribute__((ext_vector_type(8))) short short8;
typedef __attribute__((ext_vector_type(4))) float f32x4;

static __device__ __forceinline__ short f2b(float x) {
    __hip_bfloat16 h = __float2bfloat16(x);   // RNE
    short s; __builtin_memcpy(&s, &h, 2); return s;
}

// ---------------------------------------------------------------------------
// Prep: fuse W_in/W_out into w_ih (U = w_ih[:, :H] @ W_in etc), pack bf16
// weights for MFMA B-operands, precompute bias vectors.
//   gi[l][n] = S_in@U_in^T + S_out@U_out^T + rs_in[l]*c1[n] + rs_out[l]*c3[n] + cc[n]
//   gh[l][n] = h@w_hh^T + b_hh[n]
// Packed: Wrz[256][384] rows n<256: [U_in[n] | U_out[n] | w_hh[n]]  (K=384)
//         Wn1[128][256] rows c: [U_in[256+c] | U_out[256+c]]        (K=256)
//         Wn2[128][128] rows c: w_hh[256+c]                         (K=128)
// ---------------------------------------------------------------------------
__global__ __launch_bounds__(256) void prep_kernel(
    const float* __restrict__ W_in,  const float* __restrict__ b_in,
    const float* __restrict__ W_out, const float* __restrict__ b_out,
    const float* __restrict__ w_ih,  const float* __restrict__ b_ih,
    const float* __restrict__ w_hh,  const float* __restrict__ b_hh,
    const float* __restrict__ b_iah, const float* __restrict__ b_oah,
    short* __restrict__ Wrz, short* __restrict__ Wn1, short* __restrict__ Wn2,
    float* __restrict__ c1, float* __restrict__ c3,
    float* __restrict__ brz, float* __restrict__ bgin, float* __restrict__ bghn)
{
    const int tid = blockIdx.x * 256 + threadIdx.x;   // 0..49151
    const int n = tid >> 7, k = tid & 127;
    const float* wi = w_ih + (size_t)n * 256;
    float uin = 0.f, uout = 0.f;
    for (int o = 0; o < 128; ++o) {
        uin  += wi[o]       * W_in [o * 128 + k];
        uout += wi[128 + o] * W_out[o * 128 + k];
    }
    const float whh = w_hh[n * 128 + k];
    if (n < 256) {
        Wrz[n * 384 + k]       = f2b(uin);
        Wrz[n * 384 + 128 + k] = f2b(uout);
        Wrz[n * 384 + 256 + k] = f2b(whh);
    } else {
        const int c = n - 256;
        Wn1[c * 256 + k]       = f2b(uin);
        Wn1[c * 256 + 128 + k] = f2b(uout);
        Wn2[c * 128 + k]       = f2b(whh);
    }
    if (k == 0) {
        float s1 = 0.f, s2 = 0.f, s3 = 0.f, s4 = 0.f;
        for (int o = 0; o < 128; ++o) {
            s1 += wi[o] * b_in[o];        s2 += wi[o] * b_iah[o];
            s3 += wi[128 + o] * b_out[o]; s4 += wi[128 + o] * b_oah[o];
        }
        const float cc = s2 + s4 + b_ih[n];
        c1[n] = s1; c3[n] = s3;
        if (n < 256) brz[n] = cc + b_hh[n];
        else { bgin[n - 256] = cc; bghn[n - 256] = b_hh[n]; }
    }
}

// ---------------------------------------------------------------------------
// Main: one block per batch element, 128 threads = 2 waves.
//  P0: gather+normalize h (f32), write time_emb/avg, build bf16 tiles.
//  PA: S = [A_in|A_out] @ h via MFMA (K=20 padded to 32).
//  PB: rz = [S_cat|h] @ Wrz^T (K=384); gin = S_cat@Wn1^T (K=256);
//      ghn = h@Wn2^T (K=128); fused GRU epilogue in C-frag layout.
// MFMA 16x16x32 layout: A lane: row=l&15, k=(l>>4)*8+j (8 contig bf16);
// B lane: col=l&15, same k; C lane: col=l&15, row=(l>>4)*4+q (m89-verified).
// ---------------------------------------------------------------------------
__global__ __launch_bounds__(128, 2) void session_kernel(
    const int*   __restrict__ inputs, const float* __restrict__ A,
    const int*   __restrict__ times,  const float* __restrict__ emb,
    const float* __restrict__ time_tab,
    const short* __restrict__ Wrz, const short* __restrict__ Wn1,
    const short* __restrict__ Wn2,
    const float* __restrict__ c1,  const float* __restrict__ c3,
    const float* __restrict__ brz, const float* __restrict__ bgin,
    const float* __restrict__ bghn,
    float* __restrict__ out)
{
    // pitches padded to keep 16B alignment and break 32-way bank patterns
    __shared__ __align__(16) short hT  [HID][40];     // h^T[c][j] : PA B-operand
    __shared__ __align__(16) short h_rm[32][136];     // h[l][i]   : A-operand (K tail)
    __shared__ __align__(16) short adjt[2][32][40];   // adjacency : PA A-operand
    __shared__ __align__(16) short S_cat[32][264];    // [S_in|S_out] bf16 (A f32 staged here first)
    __shared__ float hf[SL][HID];                     // f32 h for gate epilogue
    __shared__ float rs[2][32];                       // adjacency rowsums
    __shared__ float sh_avg[2][HID];

    const int b = blockIdx.x;
    const int t = threadIdx.x;
    const int w = t >> 6;          // wave 0/1
    const int lam = t & 63;
    const int lane16 = lam & 15;
    const int kg = lam >> 4;       // k-group 0..3
    const int k0 = kg * 8;

    float* __restrict__ out_hidden = out;
    float* __restrict__ out_time   = out + (size_t)BATCH * SL * HID;
    float* __restrict__ out_avg    = out + (size_t)2 * BATCH * SL * HID;

    // ---- zero padding regions (0xAA garbage would poison MFMA: 0*NaN=NaN) ----
    {
        unsigned int* az = (unsigned int*)&adjt[0][0][0];
        for (int i = t; i < 2 * 32 * 40 / 2; i += 128) az[i] = 0u;
        unsigned int* hz = (unsigned int*)&h_rm[20][0];
        for (int i = t; i < 12 * 136 / 2; i += 128) hz[i] = 0u;
        unsigned int* tz = (unsigned int*)&hT[t][20];
        #pragma unroll
        for (int i = 0; i < 10; ++i) tz[i] = 0u;     // cols j=20..39
        if (t < 64) ((float*)rs)[t] = 0.f;
    }

    // ---- P0: gather + L2-norm (only gathered rows!) + time gather + avg ----
    float avg0 = 0.f, avg1 = 0.f;
    for (int i = 0; i < 10; ++i) {
        const int l   = w + 2 * i;                    // wave w owns rows w, w+2, ...
        const int idx = inputs[b * SL + l];
        const int tt  = times [b * SL + l];
        const float v0 = emb[(size_t)idx * HID + lam];
        const float v1 = emb[(size_t)idx * HID + 64 + lam];
        out_time[(size_t)(b * SL + l) * HID + lam]      = time_tab[tt * HID + lam];
        out_time[(size_t)(b * SL + l) * HID + 64 + lam] = time_tab[tt * HID + 64 + lam];
        float ss = v0 * v0 + v1 * v1;
        #pragma unroll
        for (int off = 32; off > 0; off >>= 1) ss += __shfl_xor(ss, off, 64);
        const float inv = rsqrtf(ss);
        const float h0 = v0 * inv, h1 = v1 * inv;
        hf[l][lam] = h0; hf[l][64 + lam] = h1;
        h_rm[l][lam] = f2b(h0); h_rm[l][64 + lam] = f2b(h1);
        hT[lam][l] = f2b(h0);   hT[64 + lam][l] = f2b(h1);
        avg0 += h0; avg1 += h1;
    }
    sh_avg[w][lam] = avg0; sh_avg[w][64 + lam] = avg1;

    // stage A[b] f32 into S_cat region (dead until PA epilogue)
    float* Af = (float*)&S_cat[0][0];
    {
        const float* Ab = A + (size_t)b * (SL * 2 * SL);
        for (int i = t; i < SL * 2 * SL; i += 128) Af[i] = Ab[i];
    }
    __syncthreads();

    // ---- adjacency bf16 tiles + rowsums + avg output ----
    for (int e = t; e < 800; e += 128) {
        const int m = e / 400;
        const int r2 = e - m * 400;
        const int l = r2 / 20, j = r2 - l * 20;
        adjt[m][l][j] = f2b(Af[l * 40 + m * 20 + j]);
    }
    if (t < 40) {
        const int m = t / 20, l = t % 20;
        float s = 0.f;
        for (int j = 0; j < 20; ++j) s += Af[l * 40 + m * 20 + j];
        rs[m][l] = s;
    }
    out_avg[(size_t)b * HID + t] = (sh_avg[0][t] + sh_avg[1][t]) * (1.f / SL);
    __syncthreads();

    // ---- PA: S[m] = adj[m] @ h   (M=32, K=32, N=128; wave w -> cols w*64..) ----
    f32x4 sacc[2][2][4];
    #pragma unroll
    for (int m = 0; m < 2; ++m)
        #pragma unroll
        for (int mt = 0; mt < 2; ++mt)
            #pragma unroll
            for (int nt = 0; nt < 4; ++nt) sacc[m][mt][nt] = 0.f;
    {
        short8 bF[4];
        #pragma unroll
        for (int nt = 0; nt < 4; ++nt)
            bF[nt] = *(const short8*)&hT[w * 64 + nt * 16 + lane16][k0];
        #pragma unroll
        for (int m = 0; m < 2; ++m)
            #pragma unroll
            for (int mt = 0; mt < 2; ++mt) {
                const short8 aF = *(const short8*)&adjt[m][mt * 16 + lane16][k0];
                #pragma unroll
                for (int nt = 0; nt < 4; ++nt)
                    sacc[m][mt][nt] = __builtin_amdgcn_mfma_f32_16x16x32_bf16(
                        aF, bF[nt], sacc[m][mt][nt], 0, 0, 0);
            }
        // C-frag -> S_cat bf16 (row = mt*16+kg*4+q, col = m*128 + wave cols)
        #pragma unroll
        for (int m = 0; m < 2; ++m)
            #pragma unroll
            for (int mt = 0; mt < 2; ++mt)
                #pragma unroll
                for (int nt = 0; nt < 4; ++nt)
                    #pragma unroll
                    for (int q = 0; q < 4; ++q) {
                        const int row = mt * 16 + kg * 4 + q;
                        const int col = m * 128 + w * 64 + nt * 16 + lane16;
                        S_cat[row][col] = f2b(sacc[m][mt][nt][q]);
                    }
    }
    __syncthreads();

    // ---- PB-1: rz gates, K=384 over [S_cat | h_rm] ----
    f32x4 arz[2][8];
    #pragma unroll
    for (int mt = 0; mt < 2; ++mt)
        #pragma unroll
        for (int nt = 0; nt < 8; ++nt) arz[mt][nt] = 0.f;
    #pragma unroll 2
    for (int ks = 0; ks < 12; ++ks) {
        short8 aF0, aF1;
        if (ks < 8) {
            aF0 = *(const short8*)&S_cat[lane16][ks * 32 + k0];
            aF1 = *(const short8*)&S_cat[16 + lane16][ks * 32 + k0];
        } else {
            aF0 = *(const short8*)&h_rm[lane16][(ks - 8) * 32 + k0];
            aF1 = *(const short8*)&h_rm[16 + lane16][(ks - 8) * 32 + k0];
        }
        #pragma unroll
        for (int nt = 0; nt < 8; ++nt) {
            const int nb = (nt < 4) ? (w * 64 + nt * 16) : (128 + w * 64 + (nt - 4) * 16);
            const short8 bF = *(const short8*)&Wrz[(size_t)(nb + lane16) * 384 + ks * 32 + k0];
            arz[0][nt] = __builtin_amdgcn_mfma_f32_16x16x32_bf16(aF0, bF, arz[0][nt], 0, 0, 0);
            arz[1][nt] = __builtin_amdgcn_mfma_f32_16x16x32_bf16(aF1, bF, arz[1][nt], 0, 0, 0);
        }
    }

    // rz epilogue -> sigmoid values (frag pairing: z frag = r frag + 4)
    float rv[2][4][4], zv[2][4][4];
    float rsi[2][4], rso[2][4];
    #pragma unroll
    for (int mt = 0; mt < 2; ++mt)
        #pragma unroll
        for (int q = 0; q < 4; ++q) {
            const int row = mt * 16 + kg * 4 + q;
            rsi[mt][q] = rs[0][row];
            rso[mt][q] = rs[1][row];
        }
    #pragma unroll
    for (int nt = 0; nt < 4; ++nt) {
        const int c = w * 64 + nt * 16 + lane16;
        const float c1r = c1[c],      c3r = c3[c],      br = brz[c];
        const float c1z = c1[128 + c], c3z = c3[128 + c], bz = brz[128 + c];
        #pragma unroll
        for (int mt = 0; mt < 2; ++mt)
            #pragma unroll
            for (int q = 0; q < 4; ++q) {
                const float xr = arz[mt][nt][q]     + rsi[mt][q] * c1r + rso[mt][q] * c3r + br;
                const float xz = arz[mt][nt + 4][q] + rsi[mt][q] * c1z + rso[mt][q] * c3z + bz;
                rv[mt][nt][q] = 1.f / (1.f + __expf(-xr));
                zv[mt][nt][q] = 1.f / (1.f + __expf(-xz));
            }
    }

    // ---- PB-2: gin (K=256 over S_cat) ----
    f32x4 agn[2][4];
    #pragma unroll
    for (int mt = 0; mt < 2; ++mt)
        #pragma unroll
        for (int nt = 0; nt < 4; ++nt) agn[mt][nt] = 0.f;
    #pragma unroll 2
    for (int ks = 0; ks < 8; ++ks) {
        const short8 aF0 = *(const short8*)&S_cat[lane16][ks * 32 + k0];
        const short8 aF1 = *(const short8*)&S_cat[16 + lane16][ks * 32 + k0];
        #pragma unroll
        for (int nt = 0; nt < 4; ++nt) {
            const short8 bF = *(const short8*)&Wn1[(size_t)(w * 64 + nt * 16 + lane16) * 256 + ks * 32 + k0];
            agn[0][nt] = __builtin_amdgcn_mfma_f32_16x16x32_bf16(aF0, bF, agn[0][nt], 0, 0, 0);
            agn[1][nt] = __builtin_amdgcn_mfma_f32_16x16x32_bf16(aF1, bF, agn[1][nt], 0, 0, 0);
        }
    }
    // ---- PB-3: ghn (K=128 over h) ----
    f32x4 ahn[2][4];
    #pragma unroll
    for (int mt = 0; mt < 2; ++mt)
        #pragma unroll
        for (int nt = 0; nt < 4; ++nt) ahn[mt][nt] = 0.f;
    #pragma unroll
    for (int ks = 0; ks < 4; ++ks) {
        const short8 aF0 = *(const short8*)&h_rm[lane16][ks * 32 + k0];
        const short8 aF1 = *(const short8*)&h_rm[16 + lane16][ks * 32 + k0];
        #pragma unroll
        for (int nt = 0; nt < 4; ++nt) {
            const short8 bF = *(const short8*)&Wn2[(size_t)(w * 64 + nt * 16 + lane16) * 128 + ks * 32 + k0];
            ahn[0][nt] = __builtin_amdgcn_mfma_f32_16x16x32_bf16(aF0, bF, ahn[0][nt], 0, 0, 0);
            ahn[1][nt] = __builtin_amdgcn_mfma_f32_16x16x32_bf16(aF1, bF, ahn[1][nt], 0, 0, 0);
        }
    }

    // ---- fused GRU epilogue in C-frag layout ----
    #pragma unroll
    for (int nt = 0; nt < 4; ++nt) {
        const int c = w * 64 + nt * 16 + lane16;
        const float bg = bgin[c], bh = bghn[c];
        const float c1n = c1[256 + c], c3n = c3[256 + c];
        #pragma unroll
        for (int mt = 0; mt < 2; ++mt)
            #pragma unroll
            for (int q = 0; q < 4; ++q) {
                const int row = mt * 16 + kg * 4 + q;
                const float gi_n = agn[mt][nt][q] + rsi[mt][q] * c1n + rso[mt][q] * c3n + bg;
                const float gh_n = ahn[mt][nt][q] + bh;
                const float x = gi_n + rv[mt][nt][q] * gh_n;
                const float e = __expf(2.f * x);
                const float ng = 1.f - 2.f / (e + 1.f);        // tanh, inf-safe
                const float h = hf[row < SL ? row : SL - 1][c];
                const float o = ng + zv[mt][nt][q] * (h - ng);
                if (row < SL)
                    out_hidden[(size_t)(b * SL + row) * HID + c] = o;
            }
    }
}

extern "C" void kernel_launch(void* const* d_in, const int* in_sizes, int n_in,
                              void* d_out, int out_size, void* d_ws, size_t ws_size,
                              hipStream_t stream)
{
    const int*   inputs = (const int*)  d_in[0];
    const float* A      = (const float*)d_in[1];
    const int*   times  = (const int*)  d_in[2];
    const float* emb    = (const float*)d_in[3];
    const float* ttab   = (const float*)d_in[4];
    const float* W_in   = (const float*)d_in[5];
    const float* b_in   = (const float*)d_in[6];
    const float* W_out  = (const float*)d_in[7];
    const float* b_out  = (const float*)d_in[8];
    const float* w_ih   = (const float*)d_in[9];
    const float* b_ih   = (const float*)d_in[10];
    const float* w_hh   = (const float*)d_in[11];
    const float* b_hh   = (const float*)d_in[12];
    const float* b_iah  = (const float*)d_in[13];
    const float* b_oah  = (const float*)d_in[14];
    float* out = (float*)d_out;

    char* ws = (char*)d_ws;
    short* Wrz  = (short*)(ws);            // 256*384*2  = 196608
    short* Wn1  = (short*)(ws + 196608);   // 128*256*2  =  65536
    short* Wn2  = (short*)(ws + 262144);   // 128*128*2  =  32768
    float* c1   = (float*)(ws + 294912);   // 384*4
    float* c3   = (float*)(ws + 296448);   // 384*4
    float* brz  = (float*)(ws + 297984);   // 256*4
    float* bgin = (float*)(ws + 299008);   // 128*4
    float* bghn = (float*)(ws + 299520);   // 128*4  -> total 300032 B

    hipLaunchKernelGGL(prep_kernel, dim3(192), dim3(256), 0, stream,
                       W_in, b_in, W_out, b_out, w_ih, b_ih, w_hh, b_hh, b_iah, b_oah,
                       Wrz, Wn1, Wn2, c1, c3, brz, bgin, bghn);
    hipLaunchKernelGGL(session_kernel, dim3(BATCH), dim3(128), 0, stream,
                       inputs, A, times, emb, ttab, Wrz, Wn1, Wn2,
                       c1, c3, brz, bgin, bghn, out);
}